// Round 7
// baseline (701.609 us; speedup 1.0000x reference)
//
#include <hip/hip_runtime.h>
#include <stdint.h>

typedef unsigned short u16;
typedef unsigned int u32;
typedef _Float16 f16;
typedef float v4f __attribute__((ext_vector_type(4)));
typedef f16 v8h __attribute__((ext_vector_type(8)));

#define CC 256
#define NNN 4096

__device__ __forceinline__ u16 f2h(float f) {
  union { f16 h; u16 u; } c; c.h = (f16)f; return c.u;
}
// monotone float<->uint encoding for atomicMax on fp32
__device__ __forceinline__ u32 encf(float f) {
  u32 u = __float_as_uint(f);
  return (u >> 31) ? ~u : (u | 0x80000000u);
}
__device__ __forceinline__ float decf(u32 u) {
  return (u >> 31) ? __uint_as_float(u & 0x7fffffffu) : __uint_as_float(~u);
}
__device__ __forceinline__ void async16(const void* g, void* l) {
  __builtin_amdgcn_global_load_lds(
      (const __attribute__((address_space(1))) uint32_t*)g,
      (__attribute__((address_space(3))) uint32_t*)l, 16, 0, 0);
}

// ---- W [256][256] fp32 -> Ws [256][512] fp16 (hi | lo), K(c)-fast ----
__global__ __launch_bounds__(256) void wsplit(const float* __restrict__ W,
                                              u16* __restrict__ Ws) {
  const int d = blockIdx.x, c = threadIdx.x;
  float w = W[d * 256 + c];
  f16 hi = (f16)w;
  f16 lo = (f16)(w - (float)hi);
  union { f16 h; u16 u; } ch, cl; ch.h = hi; cl.h = lo;
  Ws[d * 512 + c] = ch.u;
  Ws[d * 512 + 256 + c] = cl.u;
}

// ---- per batch: in [C][N] fp32 -> T [N][256] fp16 (transposed, K-fast),
//      and Cb [C][N] fp16 (straight copy) ----
__global__ __launch_bounds__(256) void tsplit(const float* __restrict__ in,
                                              u16* __restrict__ T,
                                              u16* __restrict__ Cb) {
  __shared__ u16 th[64][65];
  const int bb = blockIdx.z;
  const int n0 = blockIdx.x * 64;
  const int c0 = blockIdx.y * 64;
  const int tx = threadIdx.x & 63;
  const int ty = threadIdx.x >> 6;  // 0..3
  const float* ib = in + (size_t)bb * CC * NNN;
  u16* Tb = T + (size_t)bb * NNN * 256;
  u16* Cbb = Cb + (size_t)bb * CC * NNN;
#pragma unroll
  for (int k = 0; k < 16; k++) {
    int r = ty + k * 4;
    float v = ib[(size_t)(c0 + r) * NNN + n0 + tx];
    u16 h = f2h(v);
    th[r][tx] = h;
    Cbb[(size_t)(c0 + r) * NNN + n0 + tx] = h;
  }
  __syncthreads();
#pragma unroll
  for (int k = 0; k < 16; k++) {
    int r = ty + k * 4;
    Tb[(size_t)(n0 + r) * 256 + c0 + tx] = th[tx][r];
  }
}

// ---- TN GEMM over fp16, logical K=512 with per-operand k-masking.
// kA = k0 & ma ; kB = k0 & mb  -> 2-term hi/lo product on one operand.
// BK=64, XOR-swizzled LDS (8-elem chunks, pos = chunk ^ (row&7)).
// Single-buffer (cross-block overlap hides the stage drain).
// MODE 0: out = fp16 hi/lo, pitch 512 (a~).
// MODE 1: out = S fp32 + row/col max atomics; tiles XCD-clustered.
template <int MODE>
__global__ __launch_bounds__(256) void gemm_tn(
    const u16* __restrict__ A, long sAb, int pa, int ma,
    const u16* __restrict__ Bm, long sBb, int pb, int mb, int ktot,
    u16* __restrict__ outb, long sOb, float* __restrict__ S,
    u32* __restrict__ Mru, u32* __restrict__ Mcu) {
  const int bz = blockIdx.z;
  const u16* Ab = A + (size_t)bz * sAb;
  const u16* Bb = Bm + (size_t)bz * sBb;
  int m0, n0;
  if (MODE == 0) {
    m0 = blockIdx.x * 128;
    n0 = blockIdx.y * 128;
  } else {
    const int bidl = blockIdx.x + (int)gridDim.x * blockIdx.y;  // 0..1023
    const int xcd = bidl & 7, idx = bidl >> 3;
    const int mt = (xcd & 3) * 8 + (idx & 7);
    const int nt = (xcd >> 2) * 16 + (idx >> 3);
    m0 = mt * 128;
    n0 = nt * 128;
  }
  const int tid = threadIdx.x;
  const int wave = tid >> 6;
  const int lane = tid & 63;
  const int q = lane >> 4;
  const int l = lane & 15;
  const int l7 = l & 7;
  const int wm = (wave >> 1) * 64;
  const int wn = (wave & 1) * 64;
  const int sr = lane >> 3;  // row-in-group 0..7
  const int sp = lane & 7;   // LDS chunk position 0..7
  const int sg = sp ^ sr;    // global chunk index (swizzle)

  __shared__ alignas(16) u16 sA[128 * 64];
  __shared__ alignas(16) u16 sB[128 * 64];

  v4f zero = {0.f, 0.f, 0.f, 0.f};
  v4f acc[4][4];
#pragma unroll
  for (int i = 0; i < 4; i++)
#pragma unroll
    for (int j = 0; j < 4; j++) acc[i][j] = zero;

  for (int k0 = 0; k0 < ktot; k0 += 64) {
    const int kA = k0 & ma;
    const int kB = k0 & mb;
    __syncthreads();
#pragma unroll
    for (int ii = 0; ii < 4; ii++) {
      int r = wave * 32 + ii * 8 + sr;
      async16(Ab + (size_t)(m0 + r) * pa + kA + sg * 8,
              &sA[r * 64 + sp * 8]);
    }
#pragma unroll
    for (int ii = 0; ii < 4; ii++) {
      int r = wave * 32 + ii * 8 + sr;
      async16(Bb + (size_t)(n0 + r) * pb + kB + sg * 8,
              &sB[r * 64 + sp * 8]);
    }
    __syncthreads();
#pragma unroll
    for (int s = 0; s < 2; s++) {
      const int pa8 = (s * 4 + q) ^ l7;
      v8h af[4], bfr[4];
#pragma unroll
      for (int i = 0; i < 4; i++)
        af[i] = *(const v8h*)&sA[(wm + i * 16 + l) * 64 + pa8 * 8];
#pragma unroll
      for (int j = 0; j < 4; j++)
        bfr[j] = *(const v8h*)&sB[(wn + j * 16 + l) * 64 + pa8 * 8];
#pragma unroll
      for (int i = 0; i < 4; i++)
#pragma unroll
        for (int j = 0; j < 4; j++)
          acc[i][j] = __builtin_amdgcn_mfma_f32_16x16x32_f16(af[i], bfr[j],
                                                             acc[i][j], 0, 0, 0);
    }
  }

  if (MODE == 0) {
    u16* ob = outb + (size_t)bz * sOb;
#pragma unroll
    for (int i = 0; i < 4; i++)
#pragma unroll
      for (int j = 0; j < 4; j++)
#pragma unroll
        for (int r = 0; r < 4; r++) {
          int row = m0 + wm + i * 16 + q * 4 + r;
          int col = n0 + wn + j * 16 + l;
          float v = acc[i][j][r];
          f16 hi = (f16)v;
          f16 lo = (f16)(v - (float)hi);
          union { f16 h; u16 u; } ch, cl; ch.h = hi; cl.h = lo;
          ob[(size_t)row * 512 + col] = ch.u;
          ob[(size_t)row * 512 + 256 + col] = cl.u;
        }
  } else {
#pragma unroll
    for (int i = 0; i < 4; i++)
#pragma unroll
      for (int j = 0; j < 4; j++)
#pragma unroll
        for (int r = 0; r < 4; r++) {
          int row = m0 + wm + i * 16 + q * 4 + r;  // S row n
          int col = n0 + wn + j * 16 + l;          // S col m
          S[(size_t)row * NNN + col] = acc[i][j][r];
        }
    // --- row max (over this block's 128 cols) ---
    float rm[4][4];
#pragma unroll
    for (int i = 0; i < 4; i++)
#pragma unroll
      for (int r = 0; r < 4; r++)
        rm[i][r] = fmaxf(fmaxf(acc[i][0][r], acc[i][1][r]),
                         fmaxf(acc[i][2][r], acc[i][3][r]));
#pragma unroll
    for (int off = 1; off < 16; off <<= 1)
#pragma unroll
      for (int i = 0; i < 4; i++)
#pragma unroll
        for (int r = 0; r < 4; r++)
          rm[i][r] = fmaxf(rm[i][r], __shfl_xor(rm[i][r], off));
    if (l == 0) {
#pragma unroll
      for (int i = 0; i < 4; i++)
#pragma unroll
        for (int r = 0; r < 4; r++)
          atomicMax(&Mru[m0 + wm + i * 16 + q * 4 + r], encf(rm[i][r]));
    }
    // --- col max (over this block's 128 rows) ---
    float cm[4];
#pragma unroll
    for (int j = 0; j < 4; j++) {
      float v = -3e38f;
#pragma unroll
      for (int i = 0; i < 4; i++)
#pragma unroll
        for (int r = 0; r < 4; r++) v = fmaxf(v, acc[i][j][r]);
      cm[j] = v;
    }
#pragma unroll
    for (int off = 16; off < 64; off <<= 1)
#pragma unroll
      for (int j = 0; j < 4; j++) cm[j] = fmaxf(cm[j], __shfl_xor(cm[j], off));
    if (q == 0) {
#pragma unroll
      for (int j = 0; j < 4; j++)
        atomicMax(&Mcu[n0 + wn + j * 16 + l], encf(cm[j]));
    }
  }
}

// ---- FUSED full-K PV, v2: block = 512 threads (8 waves), 256c x 32x,
// k over the full 4096 in BK=128 steps (32 regions).
// V is read DIRECTLY global->VGPR (each wave owns a disjoint 32-c slice;
// per (row,s) the 4 q-lanes read 64B contiguous -> L2-coalesced; V slab is
// 2 MB and L2-resident per XCD). Only the P tile (32x x 128k fp16, 8 KB)
// goes through LDS, double-buffered -> ONE barrier per region.
// Region r: MFMA(r) from sB[r&1] + direct V; loadS(r+1); exp/pack ->
// sB[(r+1)&1]. Single hazard (P produce/consume) separated by the barrier.
// L accumulated in-block over full K -> divide + write out directly.
__global__ __launch_bounds__(512, 4) void pv_full(
    const u16* __restrict__ aV, const u16* __restrict__ bV,
    const float* __restrict__ S, const u32* __restrict__ Mru,
    const u32* __restrict__ Mcu, float* __restrict__ outA,
    float* __restrict__ outB, int batch) {
  const int lin = blockIdx.x + 128 * (blockIdx.y + 2 * blockIdx.z);  // 0..511
  const int xcd = lin & 7;
  const int which = xcd & 1;
  const int bp = (xcd >> 1) & 1;
  const int strip = (lin >> 3) + ((xcd >> 2) & 1) * 64;  // 0..127
  const int x0 = strip * 32;
  const u16* Av = (which ? bV : aV) + (size_t)(batch + bp) * (CC * NNN);
  const u32* Mst = (which ? Mru : Mcu) + bp * 4096;
  const float* Sg = S + (size_t)bp * ((size_t)NNN * NNN);
  float* Outp = (which ? outB : outA) + (size_t)(batch + bp) * CC * NNN;

  const int tid = threadIdx.x;
  const int wave = tid >> 6, lane = tid & 63, q = lane >> 4, l = lane & 15;
  const int l7 = l & 7;
  // S coords: thread owns x=xr and an 8-wide k slice (chunk g) per region.
  // which=1 (x=n rows of S): xr = tid>>4 (0..31), g = tid&15, 32B row read
  // which=0 (x=m cols of S): xr = tid&31, g = tid>>5, 8 strided dword reads
  const int xr = which ? (tid >> 4) : (tid & 31);
  const int g = which ? (tid & 15) : (tid >> 5);
  const int kb = g * 8;

  __shared__ alignas(16) u16 sB[2][32 * 128];  // P tile dbuf, 8 KB each
  __shared__ float lshf[512];
  __shared__ float Lx[32];

  v4f zero = {0.f, 0.f, 0.f, 0.f};
  v4f acc[2][2];
#pragma unroll
  for (int i = 0; i < 2; i++)
#pragma unroll
    for (int j = 0; j < 2; j++) acc[i][j] = zero;

  const float mx = decf(Mst[x0 + xr]);
  float lsum = 0.f;

  float sv[8];
  auto loadS = [&](int k0) {
    if (which) {
      const float* gp = Sg + (size_t)(x0 + xr) * NNN + k0 + kb;
      float4 v0 = ((const float4*)gp)[0];
      float4 v1 = ((const float4*)gp)[1];
      sv[0] = v0.x; sv[1] = v0.y; sv[2] = v0.z; sv[3] = v0.w;
      sv[4] = v1.x; sv[5] = v1.y; sv[6] = v1.z; sv[7] = v1.w;
    } else {
      const float* gp = Sg + (size_t)(k0 + kb) * NNN + x0 + xr;
#pragma unroll
      for (int j = 0; j < 8; j++) sv[j] = gp[(size_t)j * NNN];
    }
  };
  auto pack = [&](int buf) {
    float e[8];
#pragma unroll
    for (int t = 0; t < 8; t++) e[t] = __expf(sv[t] - mx);
#pragma unroll
    for (int t = 0; t < 8; t++) lsum += e[t];
    v8h pk;
#pragma unroll
    for (int t = 0; t < 8; t++) pk[t] = (f16)e[t];
    // P[x=xr][k=kb..kb+7] -> row xr, chunk pos = g ^ (xr&7) (XOR in low 3)
    *(v8h*)&sB[buf][xr * 128 + (g ^ (xr & 7)) * 8] = pk;
  };
  auto mfma_region = [&](int buf, int k0) {
    const u16* sBb = &sB[buf][0];
#pragma unroll
    for (int s = 0; s < 4; s++) {
      const int kc = s * 4 + q;          // global k-chunk 0..15
      const int pa8 = kc ^ l7;           // swizzled pos (XOR low 3 bits)
      v8h a0 = *(const v8h*)(Av + (size_t)(wave * 32 + l) * NNN + k0 + kc * 8);
      v8h a1 = *(const v8h*)(Av + (size_t)(wave * 32 + 16 + l) * NNN + k0 + kc * 8);
      v8h b0 = *(const v8h*)&sBb[(size_t)l * 128 + pa8 * 8];
      v8h b1 = *(const v8h*)&sBb[(size_t)(16 + l) * 128 + pa8 * 8];
      acc[0][0] = __builtin_amdgcn_mfma_f32_16x16x32_f16(a0, b0, acc[0][0], 0, 0, 0);
      acc[0][1] = __builtin_amdgcn_mfma_f32_16x16x32_f16(a0, b1, acc[0][1], 0, 0, 0);
      acc[1][0] = __builtin_amdgcn_mfma_f32_16x16x32_f16(a1, b0, acc[1][0], 0, 0, 0);
      acc[1][1] = __builtin_amdgcn_mfma_f32_16x16x32_f16(a1, b1, acc[1][1], 0, 0, 0);
    }
  };

  // prologue: P tile for region 0
  loadS(0);
  pack(0);
  __syncthreads();
  for (int r = 0; r < 32; r++) {
    mfma_region(r & 1, r * 128);
    if (r < 31) {
      loadS((r + 1) * 128);
      pack((r + 1) & 1);
    }
    __syncthreads();
  }

  // L reduction: sum the 16 per-thread partials of each x, then invert
  lshf[tid] = lsum;
  __syncthreads();
  if (tid < 32) {
    float s = 0.f;
#pragma unroll
    for (int c = 0; c < 16; c++)
      s += which ? lshf[tid * 16 + c] : lshf[c * 32 + tid];
    Lx[tid] = 1.0f / s;
  }
  __syncthreads();

  const float rl0 = Lx[l];
  const float rl1 = Lx[16 + l];
#pragma unroll
  for (int i = 0; i < 2; i++)
#pragma unroll
    for (int r = 0; r < 4; r++) {
      int c = wave * 32 + i * 16 + q * 4 + r;
      Outp[(size_t)c * NNN + x0 + l] = acc[i][0][r] * rl0;
      Outp[(size_t)c * NNN + x0 + 16 + l] = acc[i][1][r] * rl1;
    }
}

extern "C" void kernel_launch(void* const* d_in, const int* in_sizes, int n_in,
                              void* d_out, int out_size, void* d_ws,
                              size_t ws_size, hipStream_t stream) {
  const float* a = (const float*)d_in[0];
  const float* b = (const float*)d_in[1];
  const float* W = (const float*)d_in[2];
  float* out = (float*)d_out;

  char* ws = (char*)d_ws;
  u16* Ws = (u16*)(ws);                     // 262144
  u16* aT = (u16*)(ws + 262144);            // 4*4096*256*2 = 8388608
  u16* bT = (u16*)(ws + 8650752);           // 8388608
  u16* aCb = (u16*)(ws + 17039360);         // 8388608
  u16* bCb = (u16*)(ws + 25427968);         // 8388608
  u16* ats = (u16*)(ws + 33816576);         // 4*4096*512*2 = 16777216
  u32* Mru = (u32*)(ws + 50593792);         // [4][4096] u32 = 65536
  u32* Mcu = (u32*)(ws + 50659328);         // 65536
  float* Sbuf = (float*)(ws + 50724864);    // 2 batches * 64 MB = 134217728
                                            // ends ~184.9 MB

  wsplit<<<dim3(256), 256, 0, stream>>>(W, Ws);
  tsplit<<<dim3(64, 4, 4), 256, 0, stream>>>(a, aT, aCb);
  tsplit<<<dim3(64, 4, 4), 256, 0, stream>>>(b, bT, bCb);
  // a~[n][d] = sum_c aT[n][c] * (Whi+Wlo)[d][c], K=512, out fp16 hi|lo
  gemm_tn<0><<<dim3(32, 2, 4), 256, 0, stream>>>(
      aT, (long)NNN * 256, 256, 255, Ws, 0, 512, 511, 512,
      ats, (long)NNN * 512, nullptr, nullptr, nullptr);
  hipMemsetAsync(Mru, 0, 131072, stream);  // all 4 batches' Mru+Mcu

  for (int p = 0; p < 4; p += 2) {
    // S for batch p and p+1 into the two Sbuf slabs
    for (int h = 0; h < 2; h++) {
      const u16* atp = ats + (size_t)(p + h) * NNN * 512;
      const u16* btp = bT + (size_t)(p + h) * NNN * 256;
      gemm_tn<1><<<dim3(32, 32, 1), 256, 0, stream>>>(
          atp, 0, 512, 511, btp, 0, 256, 255, 512,
          nullptr, 0, Sbuf + (size_t)h * NNN * NNN,
          Mru + (p + h) * 4096, Mcu + (p + h) * 4096);
    }
    pv_full<<<dim3(128, 2, 2), 512, 0, stream>>>(
        aCb, bCb, Sbuf, Mru + p * 4096, Mcu + p * 4096,
        out, out + 4194304, p);
  }
}

// Round 8
// 384.410 us; speedup vs baseline: 1.8252x; 1.8252x over previous
//
#include <hip/hip_runtime.h>
#include <stdint.h>

typedef unsigned short u16;
typedef unsigned int u32;
typedef _Float16 f16;
typedef float v4f __attribute__((ext_vector_type(4)));
typedef f16 v8h __attribute__((ext_vector_type(8)));

#define CC 256
#define NNN 4096

__device__ __forceinline__ u16 f2h(float f) {
  union { f16 h; u16 u; } c; c.h = (f16)f; return c.u;
}
// monotone float<->uint encoding for atomicMax on fp32
__device__ __forceinline__ u32 encf(float f) {
  u32 u = __float_as_uint(f);
  return (u >> 31) ? ~u : (u | 0x80000000u);
}
__device__ __forceinline__ float decf(u32 u) {
  return (u >> 31) ? __uint_as_float(u & 0x7fffffffu) : __uint_as_float(~u);
}
__device__ __forceinline__ void async16(const void* g, void* l) {
  __builtin_amdgcn_global_load_lds(
      (const __attribute__((address_space(1))) uint32_t*)g,
      (__attribute__((address_space(3))) uint32_t*)l, 16, 0, 0);
}

// ---- W [256][256] fp32 -> Ws [256][512] fp16 (hi | lo), K(c)-fast ----
__global__ __launch_bounds__(256) void wsplit(const float* __restrict__ W,
                                              u16* __restrict__ Ws) {
  const int d = blockIdx.x, c = threadIdx.x;
  float w = W[d * 256 + c];
  f16 hi = (f16)w;
  f16 lo = (f16)(w - (float)hi);
  union { f16 h; u16 u; } ch, cl; ch.h = hi; cl.h = lo;
  Ws[d * 512 + c] = ch.u;
  Ws[d * 512 + 256 + c] = cl.u;
}

// ---- per batch: in [C][N] fp32 -> T [N][256] fp16 (transposed, K-fast),
//      and Cb [C][N] fp16 (straight copy) ----
__global__ __launch_bounds__(256) void tsplit(const float* __restrict__ in,
                                              u16* __restrict__ T,
                                              u16* __restrict__ Cb) {
  __shared__ u16 th[64][65];
  const int bb = blockIdx.z;
  const int n0 = blockIdx.x * 64;
  const int c0 = blockIdx.y * 64;
  const int tx = threadIdx.x & 63;
  const int ty = threadIdx.x >> 6;  // 0..3
  const float* ib = in + (size_t)bb * CC * NNN;
  u16* Tb = T + (size_t)bb * NNN * 256;
  u16* Cbb = Cb + (size_t)bb * CC * NNN;
#pragma unroll
  for (int k = 0; k < 16; k++) {
    int r = ty + k * 4;
    float v = ib[(size_t)(c0 + r) * NNN + n0 + tx];
    u16 h = f2h(v);
    th[r][tx] = h;
    Cbb[(size_t)(c0 + r) * NNN + n0 + tx] = h;
  }
  __syncthreads();
#pragma unroll
  for (int k = 0; k < 16; k++) {
    int r = ty + k * 4;
    Tb[(size_t)(n0 + r) * 256 + c0 + tx] = th[tx][r];
  }
}

// ---- TN GEMM over fp16, logical K with per-operand k-masking.
// kA = k0 & ma ; kB = k0 & mb  (wrap allows hi/lo double-pump on one side).
// BK=64, XOR-swizzled LDS (8-elem chunks, pos = chunk ^ (row&7)).
// MODE 0: out = a~ single fp16, pitch 256 (rounds the hi/lo-W product once).
// MODE 1: out = S fp32 + row/col max atomics; tiles XCD-clustered.
template <int MODE>
__global__ __launch_bounds__(256) void gemm_tn(
    const u16* __restrict__ A, long sAb, int pa, int ma,
    const u16* __restrict__ Bm, long sBb, int pb, int mb, int ktot,
    u16* __restrict__ outb, long sOb, float* __restrict__ S,
    u32* __restrict__ Mru, u32* __restrict__ Mcu) {
  const int bz = blockIdx.z;
  const u16* Ab = A + (size_t)bz * sAb;
  const u16* Bb = Bm + (size_t)bz * sBb;
  int m0, n0;
  if (MODE == 0) {
    m0 = blockIdx.x * 128;
    n0 = blockIdx.y * 128;
  } else {
    const int bidl = blockIdx.x + (int)gridDim.x * blockIdx.y;  // 0..1023
    const int xcd = bidl & 7, idx = bidl >> 3;
    const int mt = (xcd & 3) * 8 + (idx & 7);
    const int nt = (xcd >> 2) * 16 + (idx >> 3);
    m0 = mt * 128;
    n0 = nt * 128;
  }
  const int tid = threadIdx.x;
  const int wave = tid >> 6;
  const int lane = tid & 63;
  const int q = lane >> 4;
  const int l = lane & 15;
  const int l7 = l & 7;
  const int wm = (wave >> 1) * 64;
  const int wn = (wave & 1) * 64;
  const int sr = lane >> 3;  // row-in-group 0..7
  const int sp = lane & 7;   // LDS chunk position 0..7
  const int sg = sp ^ sr;    // global chunk index (swizzle)

  __shared__ alignas(16) u16 sA[128 * 64];
  __shared__ alignas(16) u16 sB[128 * 64];

  v4f zero = {0.f, 0.f, 0.f, 0.f};
  v4f acc[4][4];
#pragma unroll
  for (int i = 0; i < 4; i++)
#pragma unroll
    for (int j = 0; j < 4; j++) acc[i][j] = zero;

  for (int k0 = 0; k0 < ktot; k0 += 64) {
    const int kA = k0 & ma;
    const int kB = k0 & mb;
    __syncthreads();
#pragma unroll
    for (int ii = 0; ii < 4; ii++) {
      int r = wave * 32 + ii * 8 + sr;
      async16(Ab + (size_t)(m0 + r) * pa + kA + sg * 8,
              &sA[r * 64 + sp * 8]);
    }
#pragma unroll
    for (int ii = 0; ii < 4; ii++) {
      int r = wave * 32 + ii * 8 + sr;
      async16(Bb + (size_t)(n0 + r) * pb + kB + sg * 8,
              &sB[r * 64 + sp * 8]);
    }
    __syncthreads();
#pragma unroll
    for (int s = 0; s < 2; s++) {
      const int pa8 = (s * 4 + q) ^ l7;
      v8h af[4], bfr[4];
#pragma unroll
      for (int i = 0; i < 4; i++)
        af[i] = *(const v8h*)&sA[(wm + i * 16 + l) * 64 + pa8 * 8];
#pragma unroll
      for (int j = 0; j < 4; j++)
        bfr[j] = *(const v8h*)&sB[(wn + j * 16 + l) * 64 + pa8 * 8];
#pragma unroll
      for (int i = 0; i < 4; i++)
#pragma unroll
        for (int j = 0; j < 4; j++)
          acc[i][j] = __builtin_amdgcn_mfma_f32_16x16x32_f16(af[i], bfr[j],
                                                             acc[i][j], 0, 0, 0);
    }
  }

  if (MODE == 0) {
    u16* ob = outb + (size_t)bz * sOb;
#pragma unroll
    for (int i = 0; i < 4; i++)
#pragma unroll
      for (int j = 0; j < 4; j++)
#pragma unroll
        for (int r = 0; r < 4; r++) {
          int row = m0 + wm + i * 16 + q * 4 + r;
          int col = n0 + wn + j * 16 + l;
          ob[(size_t)row * 256 + col] = f2h(acc[i][j][r]);
        }
  } else {
#pragma unroll
    for (int i = 0; i < 4; i++)
#pragma unroll
      for (int j = 0; j < 4; j++)
#pragma unroll
        for (int r = 0; r < 4; r++) {
          int row = m0 + wm + i * 16 + q * 4 + r;  // S row n
          int col = n0 + wn + j * 16 + l;          // S col m
          S[(size_t)row * NNN + col] = acc[i][j][r];
        }
    // --- row max (over this block's 128 cols) ---
    float rm[4][4];
#pragma unroll
    for (int i = 0; i < 4; i++)
#pragma unroll
      for (int r = 0; r < 4; r++)
        rm[i][r] = fmaxf(fmaxf(acc[i][0][r], acc[i][1][r]),
                         fmaxf(acc[i][2][r], acc[i][3][r]));
#pragma unroll
    for (int off = 1; off < 16; off <<= 1)
#pragma unroll
      for (int i = 0; i < 4; i++)
#pragma unroll
        for (int r = 0; r < 4; r++)
          rm[i][r] = fmaxf(rm[i][r], __shfl_xor(rm[i][r], off));
    if (l == 0) {
#pragma unroll
      for (int i = 0; i < 4; i++)
#pragma unroll
        for (int r = 0; r < 4; r++)
          atomicMax(&Mru[m0 + wm + i * 16 + q * 4 + r], encf(rm[i][r]));
    }
    // --- col max (over this block's 128 rows) ---
    float cm[4];
#pragma unroll
    for (int j = 0; j < 4; j++) {
      float v = -3e38f;
#pragma unroll
      for (int i = 0; i < 4; i++)
#pragma unroll
        for (int r = 0; r < 4; r++) v = fmaxf(v, acc[i][j][r]);
      cm[j] = v;
    }
#pragma unroll
    for (int off = 16; off < 64; off <<= 1)
#pragma unroll
      for (int j = 0; j < 4; j++) cm[j] = fmaxf(cm[j], __shfl_xor(cm[j], off));
    if (q == 0) {
#pragma unroll
      for (int j = 0; j < 4; j++)
        atomicMax(&Mcu[n0 + wn + j * 16 + l], encf(cm[j]));
    }
  }
}

// ---- K-split PV partial with fused L accumulation. fp16 V/P, BK=64,
// swizzled LDS, XCD-clustered (xcd -> (which,split)). R1-baseline. ----
__global__ __launch_bounds__(256) void pv_part(
    const u16* __restrict__ aV, const u16* __restrict__ bV,
    const float* __restrict__ S, const u32* __restrict__ Mru,
    const u32* __restrict__ Mcu, float* __restrict__ part,
    float* __restrict__ Lp, int batch) {
  const int lin = blockIdx.x + 64 * (blockIdx.y + 2 * blockIdx.z);  // 0..511
  const int xcd = lin & 7;
  const int which = xcd & 1;
  const int split = xcd >> 1;
  const int x0 = (lin >> 3) * 64;
  const u16* Av = (which ? bV : aV) + (size_t)batch * (CC * NNN);
  const u32* Mst = which ? Mru : Mcu;
  float* Out = part + ((size_t)split * 2 + which) * (CC * NNN);
  float* Lpo = Lp + ((size_t)split * 2 + which) * NNN;

  const int tid = threadIdx.x;
  const int wave = tid >> 6, lane = tid & 63, q = lane >> 4, l = lane & 15;
  const int l7 = l & 7;
  const int sr = lane >> 3, sp = lane & 7, sg = sp ^ sr;
  // which=1 S-read coords: 64 x-rows x 4 chunks of 16 k
  const int xl = tid >> 2, ch = tid & 3;
  // which=0 S-read coords: 64 x-cols x 4 groups of 16 k-rows
  const int xs = tid & 63, kq = (tid >> 6) * 16;

  __shared__ alignas(16) u16 sA[256 * 64];
  __shared__ alignas(16) u16 sB[64 * 64];
  __shared__ float lsh[256];

  v4f zero = {0.f, 0.f, 0.f, 0.f};
  v4f acc[4][4];
#pragma unroll
  for (int i = 0; i < 4; i++)
#pragma unroll
    for (int j = 0; j < 4; j++) acc[i][j] = zero;

  const float mx = decf(Mst[x0 + (which ? xl : xs)]);
  float lsum = 0.f;
  const int kbeg = split * 1024;

  for (int k0 = kbeg; k0 < kbeg + 1024; k0 += 64) {
    __syncthreads();
#pragma unroll
    for (int ii = 0; ii < 8; ii++) {
      int r = wave * 64 + ii * 8 + sr;
      async16(Av + (size_t)r * NNN + k0 + sg * 8, &sA[r * 64 + sp * 8]);
    }
    if (which) {
      const float* gp = S + (size_t)(x0 + xl) * NNN + k0 + ch * 16;
      float e[16];
#pragma unroll
      for (int t4 = 0; t4 < 4; t4++) {
        float4 v = ((const float4*)gp)[t4];
        e[t4 * 4 + 0] = __expf(v.x - mx);
        e[t4 * 4 + 1] = __expf(v.y - mx);
        e[t4 * 4 + 2] = __expf(v.z - mx);
        e[t4 * 4 + 3] = __expf(v.w - mx);
      }
#pragma unroll
      for (int t = 0; t < 16; t++) lsum += e[t];
      v8h pk0, pk1;
#pragma unroll
      for (int t = 0; t < 8; t++) {
        pk0[t] = (f16)e[t];
        pk1[t] = (f16)e[t + 8];
      }
      const int g0 = ch * 2;
      *(v8h*)&sB[xl * 64 + (g0 ^ (xl & 7)) * 8] = pk0;
      *(v8h*)&sB[xl * 64 + ((g0 + 1) ^ (xl & 7)) * 8] = pk1;
    } else {
      const float* gp = S + (size_t)(k0 + kq) * NNN + x0 + xs;
      float e[16];
#pragma unroll
      for (int t = 0; t < 16; t++)
        e[t] = __expf(gp[(size_t)t * NNN] - mx);
#pragma unroll
      for (int t = 0; t < 16; t++) lsum += e[t];
      v8h pk0, pk1;
#pragma unroll
      for (int t = 0; t < 8; t++) {
        pk0[t] = (f16)e[t];
        pk1[t] = (f16)e[t + 8];
      }
      const int g0 = (tid >> 6) * 2;
      *(v8h*)&sB[xs * 64 + (g0 ^ (xs & 7)) * 8] = pk0;
      *(v8h*)&sB[xs * 64 + ((g0 + 1) ^ (xs & 7)) * 8] = pk1;
    }
    __syncthreads();
#pragma unroll
    for (int s = 0; s < 2; s++) {
      const int pa8 = (s * 4 + q) ^ l7;
      v8h af[4], bfr[4];
#pragma unroll
      for (int i = 0; i < 4; i++)
        af[i] = *(const v8h*)&sA[(wave * 64 + i * 16 + l) * 64 + pa8 * 8];
#pragma unroll
      for (int j = 0; j < 4; j++)
        bfr[j] = *(const v8h*)&sB[(j * 16 + l) * 64 + pa8 * 8];
#pragma unroll
      for (int i = 0; i < 4; i++)
#pragma unroll
        for (int j = 0; j < 4; j++)
          acc[i][j] = __builtin_amdgcn_mfma_f32_16x16x32_f16(af[i], bfr[j],
                                                             acc[i][j], 0, 0, 0);
    }
  }

  // L partial reduction: 4 threads contribute per x
  __syncthreads();
  lsh[tid] = lsum;
  __syncthreads();
  if (tid < 64) {
    float t;
    if (which)
      t = (lsh[tid * 4] + lsh[tid * 4 + 1]) + (lsh[tid * 4 + 2] + lsh[tid * 4 + 3]);
    else
      t = (lsh[tid] + lsh[tid + 64]) + (lsh[tid + 128] + lsh[tid + 192]);
    Lpo[x0 + tid] = t;
  }

#pragma unroll
  for (int i = 0; i < 4; i++)
#pragma unroll
    for (int j = 0; j < 4; j++)
#pragma unroll
      for (int r = 0; r < 4; r++) {
        int c = wave * 64 + i * 16 + q * 4 + r;
        int x = x0 + j * 16 + l;
        Out[(size_t)c * NNN + x] = acc[i][j][r];
      }
}

// ---- reduce 4 K-split partials + L partials, apply 1/L, write output ----
__global__ __launch_bounds__(256) void pv_reduce(
    const float* __restrict__ part, const float* __restrict__ Lp,
    float* __restrict__ outA, float* __restrict__ outB, int batch) {
  const int bi = blockIdx.x;  // 0..511
  const int which = bi >> 8;
  const int c = bi & 255;
  float* Out = (which ? outB : outA) + (size_t)batch * CC * NNN +
               (size_t)c * NNN;
  const float* p0 = part + (size_t)which * (CC * NNN) + (size_t)c * NNN;
  const float* l0 = Lp + (size_t)which * NNN;
  const size_t ps = 2 * (size_t)CC * NNN;
  const size_t ls = 2 * (size_t)NNN;
  const int t = threadIdx.x;
#pragma unroll
  for (int xi = 0; xi < 4; xi++) {
    int x = xi * 1024 + t * 4;
    float4 a0 = *(const float4*)(p0 + x);
    float4 a1 = *(const float4*)(p0 + ps + x);
    float4 a2 = *(const float4*)(p0 + 2 * ps + x);
    float4 a3 = *(const float4*)(p0 + 3 * ps + x);
    float4 q0 = *(const float4*)(l0 + x);
    float4 q1 = *(const float4*)(l0 + ls + x);
    float4 q2 = *(const float4*)(l0 + 2 * ls + x);
    float4 q3 = *(const float4*)(l0 + 3 * ls + x);
    float4 o;
    o.x = ((a0.x + a1.x) + (a2.x + a3.x)) / ((q0.x + q1.x) + (q2.x + q3.x));
    o.y = ((a0.y + a1.y) + (a2.y + a3.y)) / ((q0.y + q1.y) + (q2.y + q3.y));
    o.z = ((a0.z + a1.z) + (a2.z + a3.z)) / ((q0.z + q1.z) + (q2.z + q3.z));
    o.w = ((a0.w + a1.w) + (a2.w + a3.w)) / ((q0.w + q1.w) + (q2.w + q3.w));
    *(float4*)(Out + x) = o;
  }
}

extern "C" void kernel_launch(void* const* d_in, const int* in_sizes, int n_in,
                              void* d_out, int out_size, void* d_ws,
                              size_t ws_size, hipStream_t stream) {
  const float* a = (const float*)d_in[0];
  const float* b = (const float*)d_in[1];
  const float* W = (const float*)d_in[2];
  float* out = (float*)d_out;

  char* ws = (char*)d_ws;
  u16* Ws = (u16*)(ws);                     // 262144
  u16* aT = (u16*)(ws + 262144);            // 4*4096*256*2 = 8388608
  u16* bT = (u16*)(ws + 8650752);           // 8388608
  u16* aCb = (u16*)(ws + 17039360);         // 8388608
  u16* bCb = (u16*)(ws + 25427968);         // 8388608
  u16* ats = (u16*)(ws + 33816576);         // 4*4096*256*2 = 8388608 (16MB rsvd)
  u32* Mru = (u32*)(ws + 50593792);         // [4][4096] u32 = 65536
  u32* Mcu = (u32*)(ws + 50659328);         // 65536
  float* Lp = (float*)(ws + 50724864);      // 131072
  float* Sbuf = (float*)(ws + 50855936);    // 67108864
  float* Ppart = (float*)(ws + 117964800);  // 33554432 -> ends ~151.5 MB

  wsplit<<<dim3(256), 256, 0, stream>>>(W, Ws);
  tsplit<<<dim3(64, 4, 4), 256, 0, stream>>>(a, aT, aCb);
  tsplit<<<dim3(64, 4, 4), 256, 0, stream>>>(b, bT, bCb);
  // a~[n][d] = sum_c aT[n][c] * (Whi+Wlo)[d][c], K=512 hi/lo W,
  // output SINGLE fp16, pitch 256 (rounds once; b-side fp16 error dominates)
  gemm_tn<0><<<dim3(32, 2, 4), 256, 0, stream>>>(
      aT, (long)NNN * 256, 256, 255, Ws, 0, 512, 511, 512,
      ats, (long)NNN * 256, nullptr, nullptr, nullptr);
  hipMemsetAsync(Mru, 0, 131072, stream);  // all 4 batches' Mru+Mcu

  for (int p = 0; p < 4; p++) {
    const u16* atp = ats + (size_t)p * NNN * 256;
    const u16* btp = bT + (size_t)p * NNN * 256;
    // S[n][m] = sum_d a~[n][d] * b[m][d], K=256 (single fp16 both sides)
    gemm_tn<1><<<dim3(32, 32, 1), 256, 0, stream>>>(
        atp, 0, 256, 255, btp, 0, 256, 255, 256,
        nullptr, 0, Sbuf, Mru + p * 4096, Mcu + p * 4096);
    pv_part<<<dim3(64, 2, 4), 256, 0, stream>>>(
        aCb, bCb, Sbuf, Mru + p * 4096, Mcu + p * 4096, Ppart, Lp, p);
    pv_reduce<<<dim3(512), 256, 0, stream>>>(
        Ppart, Lp, out, out + 4194304, p);
  }
}